// Round 3
// baseline (549.421 us; speedup 1.0000x reference)
//
#include <hip/hip_runtime.h>

// LinearAttention: B=4, H=16, S=8192, D=64, fp32 in/out.
// out[bh,s,e] = (relu(q[s])·kv)[e] / max(relu(q[s])·ksum, 1e-6)
// kv[d][e] = sum_s relu(k[s][d]) * v[s][e];  ksum[d] = sum_s relu(k[s][d])

#define NBH 64
#define SEQ 8192
#define DIM 64
#define KV_STRIDE (DIM * DIM + DIM)     // 4160 floats per head in ws

// ---------------- Pass 1: partial kv + ksum per (bh, chunk) ----------------
// 2048 blocks = 64 heads x 32 chunks of 256 rows. Register-prefetch pipeline:
// loads for tile t+1 issue before compute of tile t (overlap HBM latency).
#define NSPLIT1 32
#define ROWS_A (SEQ / NSPLIT1)          // 256 rows per block
#define TILE_A 32                       // rows staged per iteration
#define NTILES_A (ROWS_A / TILE_A)      // 8

__global__ __launch_bounds__(256, 8) void la_kv(const float* __restrict__ K,
                                                const float* __restrict__ V,
                                                float* __restrict__ ws) {
    const int t = threadIdx.x;
    const int bh = blockIdx.x >> 5;
    const int chunk = blockIdx.x & (NSPLIT1 - 1);
    const int td = t >> 4;   // d-group 0..15
    const int te = t & 15;   // e-group 0..15

    __shared__ float sk[TILE_A * DIM];   // 8 KB
    __shared__ float sv[TILE_A * DIM];   // 8 KB

    float acc[4][4] = {};
    float ks[4] = {0.f, 0.f, 0.f, 0.f};

    const int base = bh * (SEQ * DIM) + chunk * (ROWS_A * DIM);
    const float4* K4 = reinterpret_cast<const float4*>(K + base);
    const float4* V4 = reinterpret_cast<const float4*>(V + base);

    // prefetch tile 0
    float4 ka = K4[t], kb = K4[t + 256];
    float4 va = V4[t], vb = V4[t + 256];

    for (int tile = 0; tile < NTILES_A; ++tile) {
        ka.x = fmaxf(ka.x, 0.f); ka.y = fmaxf(ka.y, 0.f);
        ka.z = fmaxf(ka.z, 0.f); ka.w = fmaxf(ka.w, 0.f);
        kb.x = fmaxf(kb.x, 0.f); kb.y = fmaxf(kb.y, 0.f);
        kb.z = fmaxf(kb.z, 0.f); kb.w = fmaxf(kb.w, 0.f);
        // ksum rides the staging regs: both chunks of this thread hit d0 = te*4
        ks[0] += ka.x + kb.x; ks[1] += ka.y + kb.y;
        ks[2] += ka.z + kb.z; ks[3] += ka.w + kb.w;
        __syncthreads();   // previous tile's LDS reads done
        *reinterpret_cast<float4*>(&sk[t * 4]) = ka;
        *reinterpret_cast<float4*>(&sk[1024 + t * 4]) = kb;
        *reinterpret_cast<float4*>(&sv[t * 4]) = va;
        *reinterpret_cast<float4*>(&sv[1024 + t * 4]) = vb;
        __syncthreads();
        if (tile < NTILES_A - 1) {   // issue next tile's loads; consumed next iter
            const int f0 = (tile + 1) * (TILE_A * DIM / 4);
            ka = K4[f0 + t]; kb = K4[f0 + t + 256];
            va = V4[f0 + t]; vb = V4[f0 + t + 256];
        }
        #pragma unroll 8
        for (int ss = 0; ss < TILE_A; ++ss) {
            // k read: 4 distinct addrs/wave (16-way bcast); v: 16 distinct (2/bank)
            float4 kk = *reinterpret_cast<const float4*>(&sk[ss * DIM + td * 4]);
            float4 vv = *reinterpret_cast<const float4*>(&sv[ss * DIM + te * 4]);
            acc[0][0] = fmaf(kk.x, vv.x, acc[0][0]);
            acc[0][1] = fmaf(kk.x, vv.y, acc[0][1]);
            acc[0][2] = fmaf(kk.x, vv.z, acc[0][2]);
            acc[0][3] = fmaf(kk.x, vv.w, acc[0][3]);
            acc[1][0] = fmaf(kk.y, vv.x, acc[1][0]);
            acc[1][1] = fmaf(kk.y, vv.y, acc[1][1]);
            acc[1][2] = fmaf(kk.y, vv.z, acc[1][2]);
            acc[1][3] = fmaf(kk.y, vv.w, acc[1][3]);
            acc[2][0] = fmaf(kk.z, vv.x, acc[2][0]);
            acc[2][1] = fmaf(kk.z, vv.y, acc[2][1]);
            acc[2][2] = fmaf(kk.z, vv.z, acc[2][2]);
            acc[2][3] = fmaf(kk.z, vv.w, acc[2][3]);
            acc[3][0] = fmaf(kk.w, vv.x, acc[3][0]);
            acc[3][1] = fmaf(kk.w, vv.y, acc[3][1]);
            acc[3][2] = fmaf(kk.w, vv.z, acc[3][2]);
            acc[3][3] = fmaf(kk.w, vv.w, acc[3][3]);
        }
    }

    float* w = ws + bh * KV_STRIDE;
    #pragma unroll
    for (int i = 0; i < 4; ++i)
        #pragma unroll
        for (int j = 0; j < 4; ++j)
            atomicAdd(&w[(td * 4 + i) * DIM + te * 4 + j], acc[i][j]);

    // ksum: reduce the 4 td-groups of this wave, then one atomic per (wave, te)
    #pragma unroll
    for (int c = 0; c < 4; ++c) {
        ks[c] += __shfl_xor(ks[c], 16);
        ks[c] += __shfl_xor(ks[c], 32);
    }
    if ((t & 48) == 0) {
        #pragma unroll
        for (int c = 0; c < 4; ++c)
            atomicAdd(&w[DIM * DIM + te * 4 + c], ks[c]);
    }
}

// ---------------- Pass 2: out = (relu(q)·kv) / max(relu(q)·ksum, 1e-6) -----
// 2048 blocks = 64 heads x 32 chunks of 256 rows; 4 threads per row (e-quads).
// No Q staging, no in-loop barriers: q read direct from global (4-lane bcast,
// coalesced); normalizer computed per-thread via sks broadcast reads.
#define NSPLIT2 32
#define ROWS_B (SEQ / NSPLIT2)          // 256 rows per block

// one d-step: 4 broadcast b128 reads of kv row d + 16 FMA
#define DSTEP(qc, dd)                                                          \
    {                                                                          \
        const float qv = (qc);                                                 \
        _Pragma("unroll")                                                      \
        for (int i = 0; i < 4; ++i) {                                          \
            float4 kv4 = *reinterpret_cast<const float4*>(                     \
                &skv[(dd) * DIM + i * 16 + te * 4]);                           \
            o[i][0] = fmaf(qv, kv4.x, o[i][0]);                                \
            o[i][1] = fmaf(qv, kv4.y, o[i][1]);                                \
            o[i][2] = fmaf(qv, kv4.z, o[i][2]);                                \
            o[i][3] = fmaf(qv, kv4.w, o[i][3]);                                \
        }                                                                      \
    }

__global__ __launch_bounds__(256, 8) void la_out(const float* __restrict__ Q,
                                                 const float* __restrict__ ws,
                                                 float* __restrict__ out) {
    const int t = threadIdx.x;
    const int bh = blockIdx.x >> 5;
    const int chunk = blockIdx.x & (NSPLIT2 - 1);
    const int te = t & 3;    // e-quad 0..3

    __shared__ float skv[DIM * DIM];     // 16 KB
    __shared__ float sks[DIM];

    const float* w = ws + bh * KV_STRIDE;
    #pragma unroll
    for (int i = 0; i < 4; ++i)
        *reinterpret_cast<float4*>(&skv[(t + i * 256) * 4]) =
            *reinterpret_cast<const float4*>(&w[(t + i * 256) * 4]);
    if (t < 16)
        *reinterpret_cast<float4*>(&sks[t * 4]) =
            *reinterpret_cast<const float4*>(&w[DIM * DIM + t * 4]);
    __syncthreads();   // only barrier in the kernel

    const float* Qb = Q + bh * (SEQ * DIM);
    float* Ob = out + bh * (SEQ * DIM);
    const int row0 = chunk * ROWS_B + (t >> 2);

    for (int iter = 0; iter < ROWS_B / 64; ++iter) {
        const int row = row0 + iter * 64;
        const float4* q4p = reinterpret_cast<const float4*>(Qb + row * DIM);
        float o[4][4] = {};
        float n = 0.f;
        #pragma unroll 4
        for (int d4 = 0; d4 < 16; ++d4) {
            float4 q = q4p[d4];                  // 4-lane broadcast, L1-coalesced
            q.x = fmaxf(q.x, 0.f); q.y = fmaxf(q.y, 0.f);
            q.z = fmaxf(q.z, 0.f); q.w = fmaxf(q.w, 0.f);
            float4 k4 = *reinterpret_cast<const float4*>(&sks[d4 * 4]);  // bcast
            n = fmaf(q.x, k4.x, n); n = fmaf(q.y, k4.y, n);
            n = fmaf(q.z, k4.z, n); n = fmaf(q.w, k4.w, n);
            DSTEP(q.x, d4 * 4 + 0);
            DSTEP(q.y, d4 * 4 + 1);
            DSTEP(q.z, d4 * 4 + 2);
            DSTEP(q.w, d4 * 4 + 3);
        }
        const float inv = 1.0f / fmaxf(n, 1e-6f);
        #pragma unroll
        for (int i = 0; i < 4; ++i) {
            float4 r;
            r.x = o[i][0] * inv; r.y = o[i][1] * inv;
            r.z = o[i][2] * inv; r.w = o[i][3] * inv;
            *reinterpret_cast<float4*>(&Ob[row * DIM + i * 16 + te * 4]) = r;
        }
    }
}

extern "C" void kernel_launch(void* const* d_in, const int* in_sizes, int n_in,
                              void* d_out, int out_size, void* d_ws, size_t ws_size,
                              hipStream_t stream) {
    const float* Q = (const float*)d_in[0];
    const float* K = (const float*)d_in[1];
    const float* V = (const float*)d_in[2];
    float* out = (float*)d_out;
    float* ws = (float*)d_ws;

    // ws is poisoned 0xAA before every timed launch: zero the kv accumulators.
    hipMemsetAsync(ws, 0, (size_t)NBH * KV_STRIDE * sizeof(float), stream);

    la_kv<<<NBH * NSPLIT1, 256, 0, stream>>>(K, V, ws);
    la_out<<<NBH * NSPLIT2, 256, 0, stream>>>(Q, ws, out);
}